// Round 1
// baseline (519.928 us; speedup 1.0000x reference)
//
#include <hip/hip_runtime.h>
#include <hip/hip_bf16.h>

// Problem constants (from reference setup_inputs):
//   n_sents=64, S=512, D=768, E=2000, P=20000, NL=128, H=512, C=3
//   L_SPAN=8, MAX_ITER=3, RATE=0.3, BETA_INTRA=0.7, BETA_INTER=0.3
// Key identities exploited:
//   feats@W1 = A1[pair1] + A2[pair2] + y[pair1] - y[pair2]
//     where A1=e_emb@W1[0:768], A2=e_emb@W1[768:1536], y=x@W1[1536:1664]
//   conf = softmax(logits).max() > 0.3 is ALWAYS true (max prob >= 1/3)
//   3rd iteration's x-update is dead code (outputs computed before update)

#define D_DIM 768
#define H_DIM 512
#define NL_DIM 128

// ---------------- extract events: e_emb[e] = mean of masked token span ----
__global__ __launch_bounds__(256) void extract_kernel(
    const float* __restrict__ sent_emb, const int* __restrict__ es,
    const int* __restrict__ st, const int* __restrict__ el,
    float* __restrict__ e_emb)
{
    int e = blockIdx.x;
    int t = threadIdx.x;
    int s = es[e];
    int start = st[e];
    int len = el[e] + 1;               // in [1,8]; start+7 <= 510 < 512, no clip needed
    const float* base = sent_emb + ((size_t)s * 512 + start) * D_DIM;
    float a0 = 0.f, a1 = 0.f, a2 = 0.f;
    for (int k = 0; k < len; ++k) {
        const float* row = base + (size_t)k * D_DIM;
        a0 += row[t];
        a1 += row[t + 256];
        a2 += row[t + 512];
    }
    float inv = 1.0f / (float)len;
    float* out = e_emb + (size_t)e * D_DIM;
    out[t]       = a0 * inv;
    out[t + 256] = a1 * inv;
    out[t + 512] = a2 * inv;
}

// ---------------- generic f32 tiled GEMM: C = [C +] relu?( A@B ) ----------
// 64x64 tile, 256 threads, 4x4 per thread, K-tile 16.
// Requirements: K % 16 == 0, N % 64 == 0, 16B-aligned pointers, lda/ldb/ldc % 4 == 0.
// flags bit0: accumulate into C; bit1: relu.
#define GBM 64
#define GBN 64
#define GBK 16
__global__ __launch_bounds__(256) void gemm_f32(
    const float* __restrict__ A, int lda,
    const float* __restrict__ B, int ldb,
    float* __restrict__ C, int ldc,
    int M, int N, int K, int flags)
{
    __shared__ float As[GBK][GBM + 4];   // +4 pad keeps 16B alignment per row, avoids conflicts
    __shared__ float Bs[GBK][GBN];
    int t = threadIdx.x;
    int m0 = blockIdx.y * GBM;
    int n0 = blockIdx.x * GBN;
    int tm = t >> 4;                     // 0..15
    int tn = t & 15;                     // 0..15
    int arow = t >> 2;                   // 0..63
    int akc  = (t & 3) * 4;              // 0,4,8,12
    int bkr  = t >> 4;                   // 0..15
    int bnc  = (t & 15) * 4;             // 0..60

    float acc[4][4];
#pragma unroll
    for (int i = 0; i < 4; ++i)
#pragma unroll
        for (int j = 0; j < 4; ++j) acc[i][j] = 0.f;

    for (int k0 = 0; k0 < K; k0 += GBK) {
        float4 av = make_float4(0.f, 0.f, 0.f, 0.f);
        if (m0 + arow < M)
            av = *(const float4*)(A + (size_t)(m0 + arow) * lda + k0 + akc);
        As[akc + 0][arow] = av.x;
        As[akc + 1][arow] = av.y;
        As[akc + 2][arow] = av.z;
        As[akc + 3][arow] = av.w;
        float4 bv = *(const float4*)(B + (size_t)(k0 + bkr) * ldb + n0 + bnc);
        *(float4*)&Bs[bkr][bnc] = bv;
        __syncthreads();
#pragma unroll
        for (int k = 0; k < GBK; ++k) {
            float4 a = *(const float4*)&As[k][tm * 4];
            float4 b = *(const float4*)&Bs[k][tn * 4];
            acc[0][0] += a.x * b.x; acc[0][1] += a.x * b.y; acc[0][2] += a.x * b.z; acc[0][3] += a.x * b.w;
            acc[1][0] += a.y * b.x; acc[1][1] += a.y * b.y; acc[1][2] += a.y * b.z; acc[1][3] += a.y * b.w;
            acc[2][0] += a.z * b.x; acc[2][1] += a.z * b.y; acc[2][2] += a.z * b.z; acc[2][3] += a.z * b.w;
            acc[3][0] += a.w * b.x; acc[3][1] += a.w * b.y; acc[3][2] += a.w * b.z; acc[3][3] += a.w * b.w;
        }
        __syncthreads();
    }
#pragma unroll
    for (int i = 0; i < 4; ++i) {
        int row = m0 + tm * 4 + i;
        if (row < M) {
            float* cp = C + (size_t)row * ldc + n0 + tn * 4;
#pragma unroll
            for (int j = 0; j < 4; ++j) {
                float v = acc[i][j];
                if (flags & 1) v += cp[j];
                if (flags & 2) v = fmaxf(v, 0.f);
                cp[j] = v;
            }
        }
    }
}

// ---------------- zero workspace region (float4) --------------------------
__global__ __launch_bounds__(256) void zero4_kernel(float4* __restrict__ p, int n4)
{
    int i = blockIdx.x * 256 + threadIdx.x;
    if (i < n4) p[i] = make_float4(0.f, 0.f, 0.f, 0.f);
}

// ---------------- fused per-pair kernel -----------------------------------
// One wave (64 lanes) per pair. h = relu(A1[p1]+A2[p2]+y[p1]-y[p2]+b1) (512)
// logits = h@W2 + b2 (3), CE, argmax, optional segment scatter.
__global__ __launch_bounds__(256) void pair_kernel(
    const float* __restrict__ A1, const float* __restrict__ A2,
    const float* __restrict__ Y, const float* __restrict__ X,
    const float* __restrict__ b1, const float* __restrict__ W2,
    const float* __restrict__ b2,
    const int* __restrict__ pair1, const int* __restrict__ pair2,
    const int* __restrict__ rel, const int* __restrict__ tgt,
    float* s_intra, float* s_inter, float* c_intra, float* c_inter,
    float* __restrict__ ce_out, float* logits_out, int P, int do_scatter)
{
    __shared__ float ce_sh[4];
    int t = threadIdx.x;
    int wave = t >> 6;
    int lane = t & 63;
    int p = blockIdx.x * 4 + wave;
    float ce = 0.f;
    if (p < P) {
        int p1 = pair1[p], p2 = pair2[p];
        int base = lane * 8;   // each lane owns 8 consecutive of the 512 dims
        float a1f[8], a2f[8], y1f[8], y2f[8], b1f[8], w2f[24];
        {
            const float4* a1p = (const float4*)(A1 + (size_t)p1 * H_DIM + base);
            const float4* a2p = (const float4*)(A2 + (size_t)p2 * H_DIM + base);
            const float4* y1p = (const float4*)(Y + (size_t)p1 * H_DIM + base);
            const float4* y2p = (const float4*)(Y + (size_t)p2 * H_DIM + base);
            const float4* b1p = (const float4*)(b1 + base);
            const float4* w2p = (const float4*)(W2 + (size_t)base * 3);
            *(float4*)&a1f[0] = a1p[0]; *(float4*)&a1f[4] = a1p[1];
            *(float4*)&a2f[0] = a2p[0]; *(float4*)&a2f[4] = a2p[1];
            *(float4*)&y1f[0] = y1p[0]; *(float4*)&y1f[4] = y1p[1];
            *(float4*)&y2f[0] = y2p[0]; *(float4*)&y2f[4] = y2p[1];
            *(float4*)&b1f[0] = b1p[0]; *(float4*)&b1f[4] = b1p[1];
#pragma unroll
            for (int q = 0; q < 6; ++q) *(float4*)&w2f[q * 4] = w2p[q];
        }
        float l0 = 0.f, l1 = 0.f, l2 = 0.f;
#pragma unroll
        for (int i = 0; i < 8; ++i) {
            float h = a1f[i] + a2f[i] + y1f[i] - y2f[i] + b1f[i];
            h = fmaxf(h, 0.f);
            l0 += h * w2f[i * 3 + 0];
            l1 += h * w2f[i * 3 + 1];
            l2 += h * w2f[i * 3 + 2];
        }
        // 64-lane butterfly: every lane ends with the full sums
#pragma unroll
        for (int off = 32; off > 0; off >>= 1) {
            l0 += __shfl_xor(l0, off);
            l1 += __shfl_xor(l1, off);
            l2 += __shfl_xor(l2, off);
        }
        l0 += b2[0]; l1 += b2[1]; l2 += b2[2];
        float m = fmaxf(l0, fmaxf(l1, l2));
        float lse = m + logf(expf(l0 - m) + expf(l1 - m) + expf(l2 - m));
        int tg = tgt[p];
        float lt = (tg == 0) ? l0 : ((tg == 1) ? l1 : l2);
        ce = lse - lt;
        if (logits_out && lane == 0) {
            logits_out[(size_t)p * 3 + 0] = l0;
            logits_out[(size_t)p * 3 + 1] = l1;
            logits_out[(size_t)p * 3 + 2] = l2;
        }
        if (do_scatter) {
            // conf = max softmax prob > 0.3 is always true (>= 1/3)
            int argm = 0; float mx = l0;
            if (l1 > mx) { mx = l1; argm = 1; }
            if (l2 > mx) { mx = l2; argm = 2; }
            if (argm != 0) {
                int r = rel[p];
                int src = (argm == 1) ? p1 : p2;
                int dst = (argm == 1) ? p2 : p1;
                float* sacc = (r == 0) ? s_intra : s_inter;
                float* cacc = (r == 0) ? c_intra : c_inter;
                const float* xs = X + (size_t)src * NL_DIM;
                float* sd = sacc + (size_t)dst * NL_DIM;
                atomicAdd(&sd[lane], xs[lane]);
                atomicAdd(&sd[lane + 64], xs[lane + 64]);
                if (lane == 0) atomicAdd(&cacc[dst], 1.0f);
            }
        }
    }
    if (lane == 0) ce_sh[wave] = ce;
    __syncthreads();
    if (t == 0) ce_out[blockIdx.x] = ce_sh[0] + ce_sh[1] + ce_sh[2] + ce_sh[3];
}

// ---------------- aggregate: scaled agg_intra / agg_inter -----------------
__global__ __launch_bounds__(256) void agg_kernel(
    const float* __restrict__ s_intra, const float* __restrict__ s_inter,
    const float* __restrict__ c_intra, const float* __restrict__ c_inter,
    const float* __restrict__ X,
    float* __restrict__ aggI, float* __restrict__ aggE, int n)
{
    int i = blockIdx.x * 256 + threadIdx.x;
    if (i >= n) return;
    int e = i >> 7;  // /128
    float ci = c_intra[e] + 1.0f;
    float cf = fmaxf(c_inter[e], 1.0f);
    aggI[i] = 0.7f * (s_intra[i] + X[i]) / ci;   // BETA_INTRA * agg_intra
    aggE[i] = 0.3f * s_inter[i] / cf;            // BETA_INTER * agg_inter
}

// ---------------- final deterministic loss reduce -------------------------
__global__ __launch_bounds__(256) void loss_kernel(
    const float* __restrict__ ce, int nblk, int P, float* __restrict__ out)
{
    int t = threadIdx.x;
    float acc = 0.f;
    for (int it = 0; it < 3; ++it) {
        float w = 1.0f / ((float)P * (float)(it + 1));
        for (int i = t; i < nblk; i += 256)
            acc += ce[(size_t)it * nblk + i] * w;
    }
    __shared__ float red[256];
    red[t] = acc;
    __syncthreads();
    for (int s = 128; s > 0; s >>= 1) {
        if (t < s) red[t] += red[t + s];
        __syncthreads();
    }
    if (t == 0) out[0] = red[0];
}

extern "C" void kernel_launch(void* const* d_in, const int* in_sizes, int n_in,
                              void* d_out, int out_size, void* d_ws, size_t ws_size,
                              hipStream_t stream)
{
    const float* sent_emb  = (const float*)d_in[0];
    const float* W_proj    = (const float*)d_in[1];
    const float* W1        = (const float*)d_in[2];
    const float* b1        = (const float*)d_in[3];
    const float* W2        = (const float*)d_in[4];
    const float* b2        = (const float*)d_in[5];
    const float* W_self    = (const float*)d_in[6];
    const float* W_intra   = (const float*)d_in[7];
    const float* W_inter   = (const float*)d_in[8];
    const int* event_sent  = (const int*)d_in[9];
    const int* event_start = (const int*)d_in[10];
    const int* event_len   = (const int*)d_in[11];
    const int* pair1       = (const int*)d_in[12];
    const int* pair2       = (const int*)d_in[13];
    const int* rel_type    = (const int*)d_in[14];
    const int* target      = (const int*)d_in[15];

    int E = in_sizes[9];    // 2000
    int P = in_sizes[12];   // 20000
    float* out = (float*)d_out;
    float* ws  = (float*)d_ws;

    // workspace layout (all offsets multiples of 4 floats -> 16B aligned)
    size_t o = 0;
    float* e_emb   = ws + o; o += (size_t)E * D_DIM;    // 2000x768
    float* A1      = ws + o; o += (size_t)E * H_DIM;    // 2000x512
    float* A2      = ws + o; o += (size_t)E * H_DIM;
    float* Yb      = ws + o; o += (size_t)E * H_DIM;
    float* X0      = ws + o; o += (size_t)E * NL_DIM;   // 2000x128
    float* X1      = ws + o; o += (size_t)E * NL_DIM;
    float* s_intra = ws + o; o += (size_t)E * NL_DIM;   // | contiguous zero
    float* s_inter = ws + o; o += (size_t)E * NL_DIM;   // | region:
    float* c_intra = ws + o; o += (size_t)E;            // | 2*E*128 + 2*E
    float* c_inter = ws + o; o += (size_t)E;            // | floats
    float* aggI    = ws + o; o += (size_t)E * NL_DIM;
    float* aggE    = ws + o; o += (size_t)E * NL_DIM;
    int NBLK = (P + 3) / 4;
    float* ceb     = ws + o; o += (size_t)3 * NBLK;

    // 1) event embeddings
    extract_kernel<<<E, 256, 0, stream>>>(sent_emb, event_sent, event_start, event_len, e_emb);

    // 2) one-time GEMMs: A1 = e@W1[0:768], A2 = e@W1[768:1536], X0 = e@W_proj
    dim3 gA(H_DIM / GBN, (E + GBM - 1) / GBM);   // (8, 32)
    dim3 gX(NL_DIM / GBN, (E + GBM - 1) / GBM);  // (2, 32)
    gemm_f32<<<gA, 256, 0, stream>>>(e_emb, D_DIM, W1, H_DIM, A1, H_DIM, E, H_DIM, D_DIM, 0);
    gemm_f32<<<gA, 256, 0, stream>>>(e_emb, D_DIM, W1 + (size_t)D_DIM * H_DIM, H_DIM, A2, H_DIM, E, H_DIM, D_DIM, 0);
    gemm_f32<<<gX, 256, 0, stream>>>(e_emb, D_DIM, W_proj, NL_DIM, X0, NL_DIM, E, NL_DIM, D_DIM, 0);

    float* xcur = X0;
    float* xnext = X1;
    int zn4 = (E * NL_DIM * 2 + E * 2) / 4;      // s_intra..c_inter contiguous
    for (int it = 0; it < 3; ++it) {
        int last = (it == 2);
        // y = x @ W1[1536:1664]  (2000x512, K=128)
        gemm_f32<<<gA, 256, 0, stream>>>(xcur, NL_DIM, W1 + (size_t)2 * D_DIM * H_DIM, H_DIM,
                                         Yb, H_DIM, E, H_DIM, NL_DIM, 0);
        if (!last)
            zero4_kernel<<<(zn4 + 255) / 256, 256, 0, stream>>>((float4*)s_intra, zn4);
        pair_kernel<<<NBLK, 256, 0, stream>>>(A1, A2, Yb, xcur, b1, W2, b2,
                                              pair1, pair2, rel_type, target,
                                              s_intra, s_inter, c_intra, c_inter,
                                              ceb + (size_t)it * NBLK,
                                              last ? (out + 1) : nullptr, P, !last);
        if (!last) {
            agg_kernel<<<(E * NL_DIM + 255) / 256, 256, 0, stream>>>(
                s_intra, s_inter, c_intra, c_inter, xcur, aggI, aggE, E * NL_DIM);
            // x_next = relu(x@W_self + aggI@W_intra + aggE@W_inter)
            gemm_f32<<<gX, 256, 0, stream>>>(xcur, NL_DIM, W_self, NL_DIM, xnext, NL_DIM, E, NL_DIM, NL_DIM, 0);
            gemm_f32<<<gX, 256, 0, stream>>>(aggI, NL_DIM, W_intra, NL_DIM, xnext, NL_DIM, E, NL_DIM, NL_DIM, 1);
            gemm_f32<<<gX, 256, 0, stream>>>(aggE, NL_DIM, W_inter, NL_DIM, xnext, NL_DIM, E, NL_DIM, NL_DIM, 1 | 2);
            float* tmp = xcur; xcur = xnext; xnext = tmp;
        }
    }
    // loss = sum_it mean(ce_it)/(it+1)
    loss_kernel<<<1, 256, 0, stream>>>(ceb, NBLK, P, out);
}

// Round 3
// 469.985 us; speedup vs baseline: 1.1063x; 1.1063x over previous
//
#include <hip/hip_runtime.h>
#include <hip/hip_bf16.h>

// Problem constants: n_sents=64, S=512, D=768, E=2000, P=20000, NL=128, H=512, C=3
// Identities exploited:
//   feats@W1 = A1[p1] + A2[p2] + y[p1] - y[p2];  A1=e@W1[0:768], A2=e@W1[768:1536], y=x@W1[1536:]
//   => precompute U = A1 + Y + b1, V = A2 - Y; then h = relu(U[p1] + V[p2])
//   conf = max softmax prob > 0.3 is ALWAYS true (3 classes => max p >= 1/3)
//   3rd iteration's x-update is dead code (loss/logits computed before update)

#define D_DIM 768
#define H_DIM 512
#define NL_DIM 128
#define KB 32          // K-tile
#define TM 64          // M-tile
#define TN 64          // N-tile

struct Smem {
    float As[KB][TM + 4];   // transposed A tile; +4 keeps rows 16B aligned
    float Bs[KB][TN];
};

// ---- shared 64x64 tile mainloop: acc += A[m0:m0+64, :K] @ Bt[:K, 0:64] ----
__device__ __forceinline__ void tile_gemm(
    const float* __restrict__ A, int lda,
    const float* __restrict__ Bt, int ldb,
    int m0, int M, int K, Smem& sm, float acc[4][4], int t)
{
    int tm = t >> 4, tn = t & 15;
    for (int k0 = 0; k0 < K; k0 += KB) {
        // A tile: 64 rows x 32 k, 2 passes of 32 rows, float4 per thread
#pragma unroll
        for (int r = 0; r < 2; ++r) {
            int row = (t >> 3) + 32 * r;
            int c4 = (t & 7) * 4;
            float4 av = make_float4(0.f, 0.f, 0.f, 0.f);
            if (m0 + row < M)
                av = *(const float4*)(A + (size_t)(m0 + row) * lda + k0 + c4);
            sm.As[c4 + 0][row] = av.x;
            sm.As[c4 + 1][row] = av.y;
            sm.As[c4 + 2][row] = av.z;
            sm.As[c4 + 3][row] = av.w;
        }
        // B tile: 32 k x 64 n, 2 passes of 16 rows
#pragma unroll
        for (int r = 0; r < 2; ++r) {
            int row = (t >> 4) + 16 * r;
            int c4 = (t & 15) * 4;
            *(float4*)&sm.Bs[row][c4] =
                *(const float4*)(Bt + (size_t)(k0 + row) * ldb + c4);
        }
        __syncthreads();
#pragma unroll
        for (int k = 0; k < KB; ++k) {
            float4 a = *(const float4*)&sm.As[k][tm * 4];
            float4 b = *(const float4*)&sm.Bs[k][tn * 4];
            acc[0][0] += a.x * b.x; acc[0][1] += a.x * b.y; acc[0][2] += a.x * b.z; acc[0][3] += a.x * b.w;
            acc[1][0] += a.y * b.x; acc[1][1] += a.y * b.y; acc[1][2] += a.y * b.z; acc[1][3] += a.y * b.w;
            acc[2][0] += a.z * b.x; acc[2][1] += a.z * b.y; acc[2][2] += a.z * b.z; acc[2][3] += a.z * b.w;
            acc[3][0] += a.w * b.x; acc[3][1] += a.w * b.y; acc[3][2] += a.w * b.z; acc[3][3] += a.w * b.w;
        }
        __syncthreads();
    }
}

// ---- fused A1|A2|X0 GEMM: segments of N map to different B/C --------------
__global__ __launch_bounds__(256) void gemm_a12x0(
    const float* __restrict__ e_emb, const float* __restrict__ W1,
    const float* __restrict__ W_proj,
    float* __restrict__ A1, float* __restrict__ A2, float* __restrict__ X0, int M)
{
    __shared__ Smem sm;
    int t = threadIdx.x;
    int bx = blockIdx.x;                // 0..17
    int m0 = blockIdx.y * TM;
    const float* Bt; float* Ct; int ldb, ldc;
    if (bx < 8)       { Bt = W1 + bx * 64;                          ldb = 512; Ct = A1 + bx * 64;        ldc = 512; }
    else if (bx < 16) { Bt = W1 + (size_t)768 * 512 + (bx - 8) * 64; ldb = 512; Ct = A2 + (bx - 8) * 64;  ldc = 512; }
    else              { Bt = W_proj + (bx - 16) * 64;               ldb = 128; Ct = X0 + (bx - 16) * 64; ldc = 128; }
    float acc[4][4] = {};
    tile_gemm(e_emb, D_DIM, Bt, ldb, m0, M, D_DIM, sm, acc, t);
    int tm = t >> 4, tn = t & 15;
#pragma unroll
    for (int i = 0; i < 4; ++i) {
        int row = m0 + tm * 4 + i;
        if (row < M)
            *(float4*)(Ct + (size_t)row * ldc + tn * 4) =
                make_float4(acc[i][0], acc[i][1], acc[i][2], acc[i][3]);
    }
}

// ---- y = x@W1[1536:], epilogue writes U = A1+y+b1, V = A2-y ---------------
__global__ __launch_bounds__(256) void gemm_y_uv(
    const float* __restrict__ x, const float* __restrict__ W1k,
    const float* __restrict__ A1, const float* __restrict__ A2,
    const float* __restrict__ b1,
    float* __restrict__ U, float* __restrict__ V, int M)
{
    __shared__ Smem sm;
    int t = threadIdx.x;
    int n0 = blockIdx.x * TN;
    int m0 = blockIdx.y * TM;
    float acc[4][4] = {};
    tile_gemm(x, NL_DIM, W1k + n0, H_DIM, m0, M, NL_DIM, sm, acc, t);
    int tm = t >> 4, tn = t & 15;
    float4 b1v = *(const float4*)(b1 + n0 + tn * 4);
#pragma unroll
    for (int i = 0; i < 4; ++i) {
        int row = m0 + tm * 4 + i;
        if (row < M) {
            size_t off = (size_t)row * H_DIM + n0 + tn * 4;
            float4 a1v = *(const float4*)(A1 + off);
            float4 a2v = *(const float4*)(A2 + off);
            float4 u, v;
            u.x = acc[i][0] + a1v.x + b1v.x;  v.x = a2v.x - acc[i][0];
            u.y = acc[i][1] + a1v.y + b1v.y;  v.y = a2v.y - acc[i][1];
            u.z = acc[i][2] + a1v.z + b1v.z;  v.z = a2v.z - acc[i][2];
            u.w = acc[i][3] + a1v.w + b1v.w;  v.w = a2v.w - acc[i][3];
            *(float4*)(U + off) = u;
            *(float4*)(V + off) = v;
        }
    }
}

// ---- xnext = relu(x@W_self + aggI@W_intra + aggE@W_inter) -----------------
__global__ __launch_bounds__(256) void gemm_update3(
    const float* __restrict__ x, const float* __restrict__ aggI, const float* __restrict__ aggE,
    const float* __restrict__ Ws, const float* __restrict__ Wi, const float* __restrict__ We,
    float* __restrict__ xn, int M)
{
    __shared__ Smem sm;
    int t = threadIdx.x;
    int n0 = blockIdx.x * TN;
    int m0 = blockIdx.y * TM;
    float acc[4][4] = {};
    tile_gemm(x,    NL_DIM, Ws + n0, NL_DIM, m0, M, NL_DIM, sm, acc, t);
    tile_gemm(aggI, NL_DIM, Wi + n0, NL_DIM, m0, M, NL_DIM, sm, acc, t);
    tile_gemm(aggE, NL_DIM, We + n0, NL_DIM, m0, M, NL_DIM, sm, acc, t);
    int tm = t >> 4, tn = t & 15;
#pragma unroll
    for (int i = 0; i < 4; ++i) {
        int row = m0 + tm * 4 + i;
        if (row < M)
            *(float4*)(xn + (size_t)row * NL_DIM + n0 + tn * 4) =
                make_float4(fmaxf(acc[i][0], 0.f), fmaxf(acc[i][1], 0.f),
                            fmaxf(acc[i][2], 0.f), fmaxf(acc[i][3], 0.f));
    }
}

// ---- extract events: e_emb[e] = mean of masked token span -----------------
__global__ __launch_bounds__(192) void extract_kernel(
    const float* __restrict__ sent_emb, const int* __restrict__ es,
    const int* __restrict__ st, const int* __restrict__ el,
    float* __restrict__ e_emb)
{
    int e = blockIdx.x;
    int t = threadIdx.x;               // 0..191, one float4 each (768 floats)
    int s = es[e];
    int start = st[e];
    int len = el[e] + 1;               // in [1,8]; start+7 <= 510, no clip needed
    const float* base = sent_emb + ((size_t)s * 512 + start) * D_DIM;
    float4 a = make_float4(0.f, 0.f, 0.f, 0.f);
    for (int k = 0; k < len; ++k) {
        float4 v = ((const float4*)(base + (size_t)k * D_DIM))[t];
        a.x += v.x; a.y += v.y; a.z += v.z; a.w += v.w;
    }
    float inv = 1.0f / (float)len;
    ((float4*)(e_emb + (size_t)e * D_DIM))[t] =
        make_float4(a.x * inv, a.y * inv, a.z * inv, a.w * inv);
}

// ---- zero a float4 region -------------------------------------------------
__global__ __launch_bounds__(256) void zero4_kernel(float4* __restrict__ p, int n4)
{
    int i = blockIdx.x * 256 + threadIdx.x;
    if (i < n4) p[i] = make_float4(0.f, 0.f, 0.f, 0.f);
}

// ---- fused per-pair kernel: 4 waves/block, 4 pairs/wave -------------------
// h = relu(U[p1] + V[p2]) (512); logits = h@W2 + b2; CE; argmax; scatter.
__global__ __launch_bounds__(256) void pair_kernel(
    const float* __restrict__ U, const float* __restrict__ V,
    const float* __restrict__ X, const float* __restrict__ W2,
    const float* __restrict__ b2,
    const int* __restrict__ pair1, const int* __restrict__ pair2,
    const int* __restrict__ rel, const int* __restrict__ tgt,
    float* s_intra, float* s_inter, float* c_intra, float* c_inter,
    float* __restrict__ ce_out, float* logits_out, int P, int do_scatter)
{
    __shared__ float ce_sh[4];
    int t = threadIdx.x;
    int wave = t >> 6;
    int lane = t & 63;
    int base = lane * 8;               // this lane's 8 dims of 512
    // W2 rows for this lane: held in registers across all 4 pairs
    float w2f[24];
    {
        const float4* w2p = (const float4*)(W2 + (size_t)base * 3);
#pragma unroll
        for (int q = 0; q < 6; ++q) *(float4*)&w2f[q * 4] = w2p[q];
    }
    float b20 = b2[0], b21 = b2[1], b22 = b2[2];
    float ce = 0.f;
    int p0 = (blockIdx.x * 4 + wave) * 4;
#pragma unroll
    for (int q = 0; q < 4; ++q) {
        int p = p0 + q;
        if (p >= P) break;
        int p1 = pair1[p], p2 = pair2[p];
        float uf[8], vf[8];
        {
            const float4* up = (const float4*)(U + (size_t)p1 * H_DIM + base);
            const float4* vp = (const float4*)(V + (size_t)p2 * H_DIM + base);
            *(float4*)&uf[0] = up[0]; *(float4*)&uf[4] = up[1];
            *(float4*)&vf[0] = vp[0]; *(float4*)&vf[4] = vp[1];
        }
        float l0 = 0.f, l1 = 0.f, l2 = 0.f;
#pragma unroll
        for (int i = 0; i < 8; ++i) {
            float h = fmaxf(uf[i] + vf[i], 0.f);
            l0 += h * w2f[i * 3 + 0];
            l1 += h * w2f[i * 3 + 1];
            l2 += h * w2f[i * 3 + 2];
        }
#pragma unroll
        for (int off = 32; off > 0; off >>= 1) {
            l0 += __shfl_xor(l0, off);
            l1 += __shfl_xor(l1, off);
            l2 += __shfl_xor(l2, off);
        }
        l0 += b20; l1 += b21; l2 += b22;
        float m = fmaxf(l0, fmaxf(l1, l2));
        float lse = m + logf(expf(l0 - m) + expf(l1 - m) + expf(l2 - m));
        int tg = tgt[p];
        float lt = (tg == 0) ? l0 : ((tg == 1) ? l1 : l2);
        ce += lse - lt;
        if (logits_out && lane == 0) {
            logits_out[(size_t)p * 3 + 0] = l0;
            logits_out[(size_t)p * 3 + 1] = l1;
            logits_out[(size_t)p * 3 + 2] = l2;
        }
        if (do_scatter) {
            int argm = 0; float mx = l0;
            if (l1 > mx) { mx = l1; argm = 1; }
            if (l2 > mx) { mx = l2; argm = 2; }
            if (argm != 0) {
                int r = rel[p];
                int src = (argm == 1) ? p1 : p2;
                int dst = (argm == 1) ? p2 : p1;
                float* sacc = (r == 0) ? s_intra : s_inter;
                float* cacc = (r == 0) ? c_intra : c_inter;
                const float* xs = X + (size_t)src * NL_DIM;
                float* sd = sacc + (size_t)dst * NL_DIM;
                atomicAdd(&sd[lane], xs[lane]);
                atomicAdd(&sd[lane + 64], xs[lane + 64]);
                if (lane == 0) atomicAdd(&cacc[dst], 1.0f);
            }
        }
    }
    if (lane == 0) ce_sh[wave] = ce;
    __syncthreads();
    if (t == 0) ce_out[blockIdx.x] = ce_sh[0] + ce_sh[1] + ce_sh[2] + ce_sh[3];
}

// ---- aggregate: scaled agg_intra / agg_inter ------------------------------
__global__ __launch_bounds__(256) void agg_kernel(
    const float* __restrict__ s_intra, const float* __restrict__ s_inter,
    const float* __restrict__ c_intra, const float* __restrict__ c_inter,
    const float* __restrict__ X,
    float* __restrict__ aggI, float* __restrict__ aggE, int n)
{
    int i = blockIdx.x * 256 + threadIdx.x;
    if (i >= n) return;
    int e = i >> 7;
    float ci = c_intra[e] + 1.0f;
    float cf = fmaxf(c_inter[e], 1.0f);
    aggI[i] = 0.7f * (s_intra[i] + X[i]) / ci;   // BETA_INTRA * agg_intra
    aggE[i] = 0.3f * s_inter[i] / cf;            // BETA_INTER * agg_inter
}

// ---- final deterministic loss reduce --------------------------------------
__global__ __launch_bounds__(256) void loss_kernel(
    const float* __restrict__ ce, int nblk, int P, float* __restrict__ out)
{
    int t = threadIdx.x;
    float acc = 0.f;
    for (int it = 0; it < 3; ++it) {
        float w = 1.0f / ((float)P * (float)(it + 1));
        for (int i = t; i < nblk; i += 256)
            acc += ce[(size_t)it * nblk + i] * w;
    }
    __shared__ float red[256];
    red[t] = acc;
    __syncthreads();
    for (int s = 128; s > 0; s >>= 1) {
        if (t < s) red[t] += red[t + s];
        __syncthreads();
    }
    if (t == 0) out[0] = red[0];
}

extern "C" void kernel_launch(void* const* d_in, const int* in_sizes, int n_in,
                              void* d_out, int out_size, void* d_ws, size_t ws_size,
                              hipStream_t stream)
{
    const float* sent_emb  = (const float*)d_in[0];
    const float* W_proj    = (const float*)d_in[1];
    const float* W1        = (const float*)d_in[2];
    const float* b1        = (const float*)d_in[3];
    const float* W2        = (const float*)d_in[4];
    const float* b2        = (const float*)d_in[5];
    const float* W_self    = (const float*)d_in[6];
    const float* W_intra   = (const float*)d_in[7];
    const float* W_inter   = (const float*)d_in[8];
    const int* event_sent  = (const int*)d_in[9];
    const int* event_start = (const int*)d_in[10];
    const int* event_len   = (const int*)d_in[11];
    const int* pair1       = (const int*)d_in[12];
    const int* pair2       = (const int*)d_in[13];
    const int* rel_type    = (const int*)d_in[14];
    const int* target      = (const int*)d_in[15];

    int E = in_sizes[9];    // 2000
    int P = in_sizes[12];   // 20000
    float* out = (float*)d_out;
    float* ws  = (float*)d_ws;

    // workspace layout (16B-aligned offsets). U aliases dead e_emb region.
    size_t o = 0;
    float* e_emb   = ws + o; o += (size_t)E * D_DIM;    // 2000x768 (dead after a12x0)
    float* A1      = ws + o; o += (size_t)E * H_DIM;    // 2000x512
    float* A2      = ws + o; o += (size_t)E * H_DIM;
    float* V       = ws + o; o += (size_t)E * H_DIM;
    float* X0      = ws + o; o += (size_t)E * NL_DIM;   // 2000x128
    float* X1      = ws + o; o += (size_t)E * NL_DIM;
    float* s_intra = ws + o; o += (size_t)E * NL_DIM;   // | contiguous zero region
    float* s_inter = ws + o; o += (size_t)E * NL_DIM;   // |
    float* c_intra = ws + o; o += (size_t)E;            // |
    float* c_inter = ws + o; o += (size_t)E;            // |
    float* aggI    = ws + o; o += (size_t)E * NL_DIM;
    float* aggE    = ws + o; o += (size_t)E * NL_DIM;
    int NBLK = (P + 15) / 16;                           // 1250
    float* ceb     = ws + o; o += (size_t)3 * NBLK;
    float* U       = e_emb;                             // alias: E*512 <= E*768

    // 1) event embeddings
    extract_kernel<<<E, 192, 0, stream>>>(sent_emb, event_sent, event_start, event_len, e_emb);

    // 2) fused one-time GEMMs: A1|A2|X0 (K=768, shared A-panel)
    dim3 gF(18, (E + TM - 1) / TM);                     // 18 x 32 = 576 blocks
    gemm_a12x0<<<gF, 256, 0, stream>>>(e_emb, W1, W_proj, A1, A2, X0, E);

    const float* W1k = W1 + (size_t)2 * D_DIM * H_DIM;  // rows 1536..1663
    dim3 gY(H_DIM / TN, (E + TM - 1) / TM);             // 8 x 32
    dim3 gU(NL_DIM / TN, (E + TM - 1) / TM);            // 2 x 32
    float* xcur = X0;
    float* xnext = X1;
    int zn4 = (E * NL_DIM * 2 + E * 2) / 4;
    for (int it = 0; it < 3; ++it) {
        int last = (it == 2);
        gemm_y_uv<<<gY, 256, 0, stream>>>(xcur, W1k, A1, A2, b1, U, V, E);
        if (!last)
            zero4_kernel<<<(zn4 + 255) / 256, 256, 0, stream>>>((float4*)s_intra, zn4);
        pair_kernel<<<NBLK, 256, 0, stream>>>(U, V, xcur, W2, b2,
                                              pair1, pair2, rel_type, target,
                                              s_intra, s_inter, c_intra, c_inter,
                                              ceb + (size_t)it * NBLK,
                                              last ? (out + 1) : nullptr, P, !last);
        if (!last) {
            agg_kernel<<<(E * NL_DIM + 255) / 256, 256, 0, stream>>>(
                s_intra, s_inter, c_intra, c_inter, xcur, aggI, aggE, E * NL_DIM);
            gemm_update3<<<gU, 256, 0, stream>>>(xcur, aggI, aggE, W_self, W_intra, W_inter, xnext, E);
            float* tmp = xcur; xcur = xnext; xnext = tmp;
        }
    }
    loss_kernel<<<1, 256, 0, stream>>>(ceb, NBLK, P, out);
}